// Round 2
// baseline (206.785 us; speedup 1.0000x reference)
//
#include <hip/hip_runtime.h>
#include <stdint.h>

// VectorQuantizer on MI355X (gfx950) — round 8
// inputs: x [64,256,32,32] fp32 (NCHW), codebook [1024,256] fp32
// outputs: q_st [64,256,32,32] fp32, loss scalar
//
// R8: m97-structure A-pipeline. R6/R7 post-mortem: compiler refuses to hold a
// register-pipelined A-stream (VGPR=60/88 vs planned 200+), exposing L2 latency
// per m-tile. Fix: A staged to LDS with global_load_lds(16B) double-buffered,
// one barrier per m-tile (compiler schedules ds_read->MFMA with counted lgkmcnt
// well — guide §5). Rows/wave raised to 64 (breg0/breg1=128 VGPR, loaded ONCE,
// direct global->reg, no LDS transpose): halves LDS-port traffic per A-byte;
// each A-frag ds_read feeds 2 MFMAs. 256 blocks x 4 waves = 1 block/CU exact.
// vq_final folded into last main block via device ticket (one less dispatch).

#define DIM 256

typedef __attribute__((ext_vector_type(8)))  short bf16x8_t;   // MFMA A/B frag (4 VGPRs)
typedef __attribute__((ext_vector_type(4)))  float f32x4_t;
typedef __attribute__((ext_vector_type(16))) float f32x16_t;   // 32x32 C/D frag

__device__ __forceinline__ uint32_t f2bf(float f) {
    union { float f; uint32_t u; } v; v.f = f;
    uint32_t r = v.u + 0x7FFFu + ((v.u >> 16) & 1u);   // RNE
    return r >> 16;
}

// ---- prep: one wave per code. Emits (a) bf16 codebook in exact MFMA A-frag
// order: entry e=(mt*16+ks)*64+lane2 holds cb[mt*32+(lane2&31)][ks*16+(lane2>>5)*8+j],
// and (b) -0.5*||c||^2 in C/D-register order (nh_ord[mt*32 + half*16 + r]).
// Also zeroes loss_accum and the completion ticket.
__global__ __launch_bounds__(256) void vq_prep(const float* __restrict__ cb,
                                               char* __restrict__ cbsw,
                                               float* __restrict__ nh_ord,
                                               float* __restrict__ loss_accum,
                                               unsigned* __restrict__ done) {
    if (blockIdx.x == 0 && threadIdx.x == 0) { *loss_accum = 0.f; *done = 0u; }

    const int code = blockIdx.x * 4 + (threadIdx.x >> 6);
    const int l    = threadIdx.x & 63;               // holds d = 4l..4l+3
    const f32x4_t v = ((const f32x4_t*)(cb + code * DIM))[l];
    float sq = v.x * v.x + v.y * v.y + v.z * v.z + v.w * v.w;

    const int mt = code >> 5;
    const int ks = l >> 2;               // d/16
    const int hl = (l >> 1) & 1;         // (d%16)/8
    const uint32_t ebyte = (uint32_t)(((mt * 16 + ks) * 64 + (code & 31) + 32 * hl) * 16
                                      + (l & 1) * 8);
    uint2 o;
    o.x = f2bf(v.x) | (f2bf(v.y) << 16);
    o.y = f2bf(v.z) | (f2bf(v.w) << 16);
    *(uint2*)(cbsw + ebyte) = o;

    #pragma unroll
    for (int m = 32; m; m >>= 1) sq += __shfl_xor(sq, m);
    if (l == 0) {
        const int rw = code & 31;
        const int h4 = (rw >> 2) & 1;
        const int r  = (rw & 3) | ((rw >> 3) << 2);
        nh_ord[mt * 32 + h4 * 16 + r] = -0.5f * sq;
    }
}

// ---- main: 256 blocks x 256 threads; block = 256 hw rows; wave w owns rows
// w*64..w*64+63 (two 32-row n-tiles) and sweeps all 1024 codes.
__global__ __launch_bounds__(256, 2) void vq_main(const float* __restrict__ x,
                                                  const float* __restrict__ cb,
                                                  const char* __restrict__ cbsw,
                                                  const float* __restrict__ nh_ord,
                                                  float* __restrict__ out,
                                                  float* __restrict__ loss_accum,
                                                  unsigned* __restrict__ done) {
    __shared__ __align__(16) uint32_t abuf[2][4096];   // 2 x 16 KB A double-buffer
    __shared__ int sfin[256];

    const int t    = threadIdx.x;
    const int w    = t >> 6;
    const int lane = t & 63;
    const int colr = lane & 31;          // code-row / hw-col within tile
    const int hi   = lane >> 5;          // k-half
    const int n0   = blockIdx.x << 8;    // 256 rows per block
    const int batch = n0 >> 10;
    const int hw0   = n0 & 1023;

    // ---- issue stage of m-tile 0 into abuf[0] (in flight during B-load)
    {
        const char* src = cbsw + (size_t)(w * 256 + lane) * 16;
        #pragma unroll
        for (int q = 0; q < 4; ++q)
            __builtin_amdgcn_global_load_lds(
                (const __attribute__((address_space(1))) uint32_t*)(src + q * 1024),
                (__attribute__((address_space(3))) uint32_t*)(&abuf[0][(w * 256 + q * 64) * 4]),
                16, 0, 0);
    }

    // ---- B-load: direct global->reg, f2bf in-register. Lane covers
    // rows w*64+nt*32+colr, d = ks*16+hi*8+j. Each scalar load instr = two full
    // 128B segments (lanes 0-31 consecutive hw at d, lanes 32-63 at d+8).
    float sq = 0.f;
    bf16x8_t breg0[16], breg1[16];
    {
        const float* xw = x + (size_t)batch * (DIM * 1024) + hw0 + w * 64 + colr;
        #pragma unroll
        for (int nt = 0; nt < 2; ++nt) {
            const float* xp = xw + nt * 32;
            #pragma unroll
            for (int ks = 0; ks < 16; ++ks) {
                const float* dp = xp + (size_t)(ks * 16 + hi * 8) * 1024;
                float a[8];
                #pragma unroll
                for (int j = 0; j < 8; ++j) {
                    a[j] = dp[(size_t)j * 1024];
                    sq += a[j] * a[j];
                }
                uint4 pk;
                pk.x = f2bf(a[0]) | (f2bf(a[1]) << 16);
                pk.y = f2bf(a[2]) | (f2bf(a[3]) << 16);
                pk.z = f2bf(a[4]) | (f2bf(a[5]) << 16);
                pk.w = f2bf(a[6]) | (f2bf(a[7]) << 16);
                union { uint4 u; bf16x8_t v; } cv; cv.u = pk;
                if (nt == 0) breg0[ks] = cv.v; else breg1[ks] = cv.v;
            }
        }
        #pragma unroll
        for (int m = 32; m; m >>= 1) sq += __shfl_xor(sq, m);
        // sq now = sum ||x_row||^2 over this wave's 64 rows (each (row,d) once)
    }
    __syncthreads();   // drains vmcnt: abuf[0] staged, all waves ready

    // ---- K-loop: 32 m-tiles, A from LDS (dbuf), B from regs, 1 barrier/iter
    float best0 = -3.0e38f, best1 = -3.0e38f;
    int   bi0 = 0, bi1 = 0;
    const f32x4_t* nhp = (const f32x4_t*)(nh_ord + hi * 16);

    #pragma unroll 1
    for (int mt = 0; mt < 32; ++mt) {
        const uint32_t* ab = &abuf[mt & 1][0];

        // prefetch next m-tile into the other buffer (completes by the barrier)
        if (mt < 31) {
            const char* src = cbsw + (size_t)((mt + 1) * 1024 + w * 256 + lane) * 16;
            uint32_t* db = &abuf[(mt + 1) & 1][0];
            #pragma unroll
            for (int q = 0; q < 4; ++q)
                __builtin_amdgcn_global_load_lds(
                    (const __attribute__((address_space(1))) uint32_t*)(src + q * 1024),
                    (__attribute__((address_space(3))) uint32_t*)(db + (w * 256 + q * 64) * 4),
                    16, 0, 0);
        }

        const f32x4_t nh0 = nhp[0], nh1 = nhp[1], nh2 = nhp[2], nh3 = nhp[3];
        f32x16_t c0, c1;
        #pragma unroll
        for (int r = 0; r < 16; ++r) { c0[r] = 0.f; c1[r] = 0.f; }

        #pragma unroll
        for (int ks = 0; ks < 16; ++ks) {
            const bf16x8_t a = *(const bf16x8_t*)(ab + ks * 256 + lane * 4);
            c0 = __builtin_amdgcn_mfma_f32_32x32x16_bf16(a, breg0[ks], c0, 0, 0, 0);
            c1 = __builtin_amdgcn_mfma_f32_32x32x16_bf16(a, breg1[ks], c1, 0, 0, 0);
        }

        // scan: score = dot - 0.5||c||^2; ascending code order, strict > keeps min idx
        const int cbase = mt * 32 + hi * 4;
        #pragma unroll
        for (int r = 0; r < 16; ++r) {
            const float nv = (r < 4) ? nh0[r] : (r < 8) ? nh1[r - 4]
                           : (r < 12) ? nh2[r - 8] : nh3[r - 12];
            const int code = cbase + (r & 3) + 8 * (r >> 2);
            const float v0 = c0[r] + nv;
            const float v1 = c1[r] + nv;
            if (v0 > best0) { best0 = v0; bi0 = code; }
            if (v1 > best1) { best1 = v1; bi1 = code; }
        }
        nhp += 8;
        __syncthreads();   // next buffer staged + everyone done with current
    }

    // ---- combine the two k-half lanes (same hw row, disjoint code subsets)
    {
        float ov = __shfl_xor(best0, 32); int oi = __shfl_xor(bi0, 32);
        if (ov > best0 || (ov == best0 && oi < bi0)) { best0 = ov; bi0 = oi; }
        ov = __shfl_xor(best1, 32); oi = __shfl_xor(bi1, 32);
        if (ov > best1 || (ov == best1 && oi < bi1)) { best1 = ov; bi1 = oi; }
    }
    if (lane < 32) {
        sfin[w * 64 + lane]      = bi0;
        sfin[w * 64 + 32 + lane] = bi1;
    }

    // ---- per-wave loss partial: twin lanes duplicate each row's best, so
    // sum(-(best0+best1)) over 64 lanes = -2*sum_rows(best); sq adds ||x||^2.
    {
        float ls = -(best0 + best1);
        #pragma unroll
        for (int m = 32; m; m >>= 1) ls += __shfl_xor(ls, m);
        if (lane == 0) atomicAdd(loss_accum, ls + sq);
    }
    __syncthreads();

    // ---- epilogue: gather fp32 codebook rows, dwordx4 stores along hw
    {
        const int q  = t & 63;     // rows 4q..4q+3 of 256
        const int dg = t >> 6;     // 0..3 -> d in [dg*64, dg*64+64)
        const int c0i = sfin[4 * q + 0], c1i = sfin[4 * q + 1];
        const int c2i = sfin[4 * q + 2], c3i = sfin[4 * q + 3];
        const float* r0 = cb + c0i * DIM;
        const float* r1 = cb + c1i * DIM;
        const float* r2 = cb + c2i * DIM;
        const float* r3 = cb + c3i * DIM;
        float* ob = out + (size_t)batch * (DIM * 1024) + hw0 + 4 * q;
        #pragma unroll 4
        for (int j = 0; j < 64; ++j) {
            const int d = dg * 64 + j;
            f32x4_t v; v.x = r0[d]; v.y = r1[d]; v.z = r2[d]; v.w = r3[d];
            *(f32x4_t*)(ob + (size_t)d * 1024) = v;
        }
    }

    // ---- last block to finish computes the final loss (replaces vq_final)
    __threadfence();
    if (t == 0) {
        const unsigned old = atomicAdd(done, 1u);
        if (old == 255u) {
            __threadfence();
            const float s = atomicAdd(loss_accum, 0.f);   // coherent read
            out[16777216] = 1.25f * s / 16777216.f;
        }
    }
}

extern "C" void kernel_launch(void* const* d_in, const int* in_sizes, int n_in,
                              void* d_out, int out_size, void* d_ws, size_t ws_size,
                              hipStream_t stream) {
    const float* x  = (const float*)d_in[0];   // [64,256,32,32]
    const float* cb = (const float*)d_in[1];   // [1024,256]
    float* out = (float*)d_out;                // 16777216 + 1

    char* ws = (char*)d_ws;
    float*    loss_accum = (float*)ws;                        // 4 B
    unsigned* done       = (unsigned*)(ws + 64);              // 4 B
    char*     cbsw       = ws + 1024;                         // 512 KB, A-frag order
    float*    nh_ord     = (float*)(ws + 1024 + 512 * 1024);  // 4 KB

    vq_prep<<<dim3(256), dim3(256), 0, stream>>>(cb, cbsw, nh_ord, loss_accum, done);
    vq_main<<<dim3(256), dim3(256), 0, stream>>>(x, cb, cbsw, nh_ord, out,
                                                 loss_accum, done);
}